// Round 16
// baseline (658.141 us; speedup 1.0000x reference)
//
#include <hip/hip_runtime.h>
#include <hip/hip_cooperative_groups.h>

namespace cg = cooperative_groups;

#define NB   4
#define H_IN 14
#define W_IN 14
#define FIN  32
#define DI   8
#define F    32
#define C    288   // 3*3*32
#define DO   16
#define HO   12
#define WO   12
#define NPOS (NB*HO*WO)   // 576
#define EPS  1e-7f

#define CH   16            // c-chunks
#define CC   (C/CH)        // 18
#define GRID (CH*(NPOS/8)) // 1152

#define XELE  (NB*H_IN*W_IN*FIN*DI)            // 200,704
#define W2H_BYTES  ((size_t)F*C*DO*DI*2)       // 2,359,296
#define XH_BYTES   ((size_t)XELE*2)            // 401,408
#define CENT_BYTES ((size_t)NPOS*F*DO*4)       // 1,179,648
#define PART_BYTES ((size_t)CH*CENT_BYTES)     // 18,874,368 (part1; part2 aliases)
#define OUT1_BYTES CENT_BYTES

#define WBLK ((F*C*DO)/256)                    // 576 conversion blocks for W
#define XBLK ((XELE/4 + 255)/256)              // 196 conversion blocks for x

typedef _Float16 h2 __attribute__((ext_vector_type(2)));

__device__ __forceinline__ unsigned int pack2(float a, float b) {
    h2 v; v.x = (_Float16)a; v.y = (_Float16)b;
    return __builtin_bit_cast(unsigned int, v);
}

// 8-term fp16 dot with fp32 accumulate
__device__ __forceinline__ float dot8h(const uint4 w, const uint4 v, float acc) {
#if __has_builtin(__builtin_amdgcn_fdot2)
    acc = __builtin_amdgcn_fdot2(__builtin_bit_cast(h2, w.x), __builtin_bit_cast(h2, v.x), acc, false);
    acc = __builtin_amdgcn_fdot2(__builtin_bit_cast(h2, w.y), __builtin_bit_cast(h2, v.y), acc, false);
    acc = __builtin_amdgcn_fdot2(__builtin_bit_cast(h2, w.z), __builtin_bit_cast(h2, v.z), acc, false);
    acc = __builtin_amdgcn_fdot2(__builtin_bit_cast(h2, w.w), __builtin_bit_cast(h2, v.w), acc, false);
#else
    const h2 w0 = __builtin_bit_cast(h2, w.x), v0 = __builtin_bit_cast(h2, v.x);
    const h2 w1 = __builtin_bit_cast(h2, w.y), v1 = __builtin_bit_cast(h2, v.y);
    const h2 w2 = __builtin_bit_cast(h2, w.z), v2 = __builtin_bit_cast(h2, v.z);
    const h2 w3 = __builtin_bit_cast(h2, w.w), v3 = __builtin_bit_cast(h2, v.w);
    acc += (float)w0.x*(float)v0.x + (float)w0.y*(float)v0.y
         + (float)w1.x*(float)v1.x + (float)w1.y*(float)v1.y
         + (float)w2.x*(float)v2.x + (float)w2.y*(float)v2.y
         + (float)w3.x*(float)v3.x + (float)w3.y*(float)v3.y;
#endif
    return acc;
}

__device__ __forceinline__ int xbase_of(int pos) {
    const int b = pos/(HO*WO), rem = pos%(HO*WO), ho = rem/WO, wo = rem%WO;
    return ((b*H_IN + ho)*W_IN + wo)*FIN*DI;
}

__device__ __forceinline__ int coff_of(int c) {
    const int slab = c >> 5, fin = c & 31;
    const int kh = slab/3, kw = slab%3;
    return (kh*W_IN + kw)*FIN*DI + fin*DI;
}

// ================= fused cooperative kernel: conv -> cent1 -> out1 -> routing -> store
__global__ __launch_bounds__(256, 5) void fusedk(
    const float* __restrict__ Wt, const float* __restrict__ x,
    unsigned short* __restrict__ W2h, unsigned short* __restrict__ xh,
    float* __restrict__ part,            // part1; re-used as part2 after PO
    float* __restrict__ out1,
    float* __restrict__ out)
{
    __shared__ union {
        struct { float red[2][4][8][32]; float ccs[2][8][32]; } p2;   // 10 KB
        struct { float red[4][32]; float scale[32]; } po;             // 640 B
    } sm;

    cg::grid_group grid = cg::this_grid();
    const int tid = threadIdx.x;
    const int blk = blockIdx.x;

    // ---------------- P0: fp32 -> fp16 conversion ----------------
    if (blk < WBLK) {
        const int idx = blk*256 + tid;                 // (c*DO+o)*F+f
        const int f = idx & 31, o = (idx >> 5) & 15, c = idx >> 9;
        const float* src = Wt + ((size_t)(f*C + c)*DO + o)*DI;
        const float4 a  = *(const float4*)src;
        const float4 bb = *(const float4*)(src + 4);
        uint4 r;
        r.x = pack2(a.x, a.y);   r.y = pack2(a.z, a.w);
        r.z = pack2(bb.x, bb.y); r.w = pack2(bb.z, bb.w);
        ((uint4*)W2h)[idx] = r;
    } else if (blk < WBLK + XBLK) {
        const int i = (blk - WBLK)*256 + tid;
        if (i < XELE/4) {
            const float4 v = ((const float4*)x)[i];
            uint2 o;
            o.x = pack2(v.x, v.y); o.y = pack2(v.z, v.w);
            ((uint2*)xh)[i] = o;
        }
    }
    grid.sync();

    const int f  = tid & 31;
    const int og = tid >> 5;            // 0..7
    const int ch = blk & (CH-1);
    const int pg = blk >> 4;            // 0..71

    // ---------------- P1: cent1 partials (kern1n body) ----------------
    {
        const int o0 = 2*og, o1 = o0 + 1;
        int xoff[8];                    // block-uniform -> SGPRs
        #pragma unroll
        for (int p = 0; p < 8; ++p) xoff[p] = xbase_of(pg*8 + p);

        const uint4* W2h4 = (const uint4*)W2h;
        const int c0 = ch*CC;

        float acc0[8], acc1[8];
        #pragma unroll
        for (int p = 0; p < 8; ++p) { acc0[p] = 0.f; acc1[p] = 0.f; }

        #pragma unroll 1
        for (int cl = 0; cl < CC; ++cl) {
            const int c = c0 + cl;
            const int coff = coff_of(c);
            const uint4 w0 = W2h4[(size_t)(c*DO + o0)*F + f];
            const uint4 w1 = W2h4[(size_t)(c*DO + o1)*F + f];
            #pragma unroll
            for (int p = 0; p < 8; ++p) {
                const uint4 xv = *(const uint4*)(xh + xoff[p] + coff);  // uniform
                acc0[p] = dot8h(w0, xv, acc0[p]);
                acc1[p] = dot8h(w1, xv, acc1[p]);
            }
        }
        #pragma unroll
        for (int p = 0; p < 8; ++p) {
            const size_t base = ((size_t)(ch*NPOS + pg*8 + p))*DO;
            part[(base + o0)*F + f] = acc0[p];
            part[(base + o1)*F + f] = acc1[p];
        }
    }
    grid.sync();

    // ---------------- PO: out1 = squash(sum_ch part / 32) ----------------
    if (blk < NPOS) {
        const int pos = blk;
        float s0 = 0.f, s1 = 0.f;       // o = og and og+8
        #pragma unroll
        for (int k = 0; k < CH; ++k) {
            const float* sp = part + (size_t)(k*NPOS + pos)*512;
            s0 += sp[og*F + f];
            s1 += sp[(og + 8)*F + f];
        }
        s0 *= (1.f/32.f); s1 *= (1.f/32.f);

        float sq = s0*s0 + s1*s1;
        sq += __shfl_xor(sq, 32);       // combine og pair within wave
        const int wv = tid >> 6;
        if (((tid >> 5) & 1) == 0) sm.po.red[wv][f] = sq;
        __syncthreads();
        if (tid < 32) {
            const float sn = sm.po.red[0][tid] + sm.po.red[1][tid]
                           + sm.po.red[2][tid] + sm.po.red[3][tid];
            sm.po.scale[tid] = (sn/(1.f + sn)) * rsqrtf(sn + EPS);
        }
        __syncthreads();
        const float sc = sm.po.scale[f];
        out1[(size_t)pos*512 + f*DO + og]     = s0 * sc;
        out1[(size_t)pos*512 + f*DO + og + 8] = s1 * sc;
    }
    grid.sync();

    // ---------------- P2: routing iter-2 (kern2n body, R15) ----------------
    {
        const int o0 = 2*og, o1 = o0 + 1;
        const int wv = tid >> 6;
        const int half = (tid >> 5) & 1;

        int xoff[8];
        #pragma unroll
        for (int p = 0; p < 8; ++p) xoff[p] = xbase_of(pg*8 + p);

        float u0[8], u1[8];
        #pragma unroll
        for (int p = 0; p < 8; ++p) {
            const float* up = out1 + (size_t)(pg*8 + p)*512 + f*DO;
            u0[p] = up[o0];
            u1[p] = up[o1];
        }

        const uint4* W2h4 = (const uint4*)W2h;
        const int c0 = ch*CC;

        float acc0[8], acc1[8];
        #pragma unroll
        for (int p = 0; p < 8; ++p) { acc0[p] = 0.f; acc1[p] = 0.f; }

        __syncthreads();
        #pragma unroll 1
        for (int cl = 0; cl < CC; ++cl) {
            const int c = c0 + cl;
            const int buf = cl & 1;
            const int coff = coff_of(c);
            const uint4 w0 = W2h4[(size_t)(c*DO + o0)*F + f];
            const uint4 w1 = W2h4[(size_t)(c*DO + o1)*F + f];

            float pred0[8], pred1[8];
            #pragma unroll
            for (int p = 0; p < 8; ++p) {
                const uint4 xv = *(const uint4*)(xh + xoff[p] + coff);  // uniform
                pred0[p] = dot8h(w0, xv, 0.f);
                pred1[p] = dot8h(w1, xv, 0.f);
            }

            #pragma unroll
            for (int p = 0; p < 8; ++p) {
                float ap = pred0[p]*u0[p] + pred1[p]*u1[p];
                ap += __shfl_xor(ap, 32);
                if (half == 0) sm.p2.red[buf][wv][p][f] = ap;
            }
            __syncthreads();

            {
                const int p2 = tid >> 5, f2 = tid & 31;
                const float agr = sm.p2.red[buf][0][p2][f2] + sm.p2.red[buf][1][p2][f2]
                                + sm.p2.red[buf][2][p2][f2] + sm.p2.red[buf][3][p2][f2];
                float m = agr;
                m = fmaxf(m, __shfl_xor(m, 1));
                m = fmaxf(m, __shfl_xor(m, 2));
                m = fmaxf(m, __shfl_xor(m, 4));
                m = fmaxf(m, __shfl_xor(m, 8));
                m = fmaxf(m, __shfl_xor(m, 16));
                const float e = __expf(agr - m);
                float s = e;
                s += __shfl_xor(s, 1);
                s += __shfl_xor(s, 2);
                s += __shfl_xor(s, 4);
                s += __shfl_xor(s, 8);
                s += __shfl_xor(s, 16);
                sm.p2.ccs[buf][p2][f2] = e / s;
            }
            __syncthreads();

            #pragma unroll
            for (int p = 0; p < 8; ++p) {
                const float cv = sm.p2.ccs[buf][p][f];
                acc0[p] += cv*pred0[p];
                acc1[p] += cv*pred1[p];
            }
        }

        #pragma unroll
        for (int p = 0; p < 8; ++p) {
            const size_t base = ((size_t)(ch*NPOS + pg*8 + p))*DO;
            part[(base + o0)*F + f] = acc0[p];
            part[(base + o1)*F + f] = acc1[p];
        }
    }
    grid.sync();

    // ---------------- P3: reduce cent2, squash, store ----------------
    if (blk < NPOS/8) {
        const int p = tid >> 5;
        const int pos = blk*8 + p;
        float cent[DO];
        #pragma unroll
        for (int o = 0; o < DO; ++o) cent[o] = 0.f;
        #pragma unroll 1
        for (int k = 0; k < CH; ++k) {
            const float* s = part + (size_t)(k*NPOS + pos)*512 + f;
            #pragma unroll
            for (int o = 0; o < DO; ++o) cent[o] += s[o*F];
        }
        float sn = 0.f;
        #pragma unroll
        for (int o = 0; o < DO; ++o) sn += cent[o]*cent[o];
        const float sc = (sn/(1.f + sn)) * rsqrtf(sn + EPS);
        float* dst = out + ((size_t)pos*F + f)*DO;
        #pragma unroll
        for (int o = 0; o < DO; ++o) dst[o] = cent[o]*sc;
    }
}

// ================= fallback path: exact R15 5-kernel pipeline =================
__global__ __launch_bounds__(256) void kernConv(const float* __restrict__ Wt,
                                                unsigned short* __restrict__ W2h,
                                                const float* __restrict__ x,
                                                unsigned short* __restrict__ xh) {
    const int b = blockIdx.x;
    if (b < WBLK) {
        const int idx = b*256 + threadIdx.x;
        const int f = idx & 31, o = (idx >> 5) & 15, c = idx >> 9;
        const float* src = Wt + ((size_t)(f*C + c)*DO + o)*DI;
        const float4 a = *(const float4*)src;
        const float4 bb = *(const float4*)(src + 4);
        uint4 r;
        r.x = pack2(a.x, a.y);  r.y = pack2(a.z, a.w);
        r.z = pack2(bb.x, bb.y); r.w = pack2(bb.z, bb.w);
        ((uint4*)W2h)[idx] = r;
    } else {
        const int i = (b - WBLK)*256 + threadIdx.x;
        if (i < XELE/4) {
            const float4 v = ((const float4*)x)[i];
            uint2 o;
            o.x = pack2(v.x, v.y); o.y = pack2(v.z, v.w);
            ((uint2*)xh)[i] = o;
        }
    }
}

__global__ __launch_bounds__(256, 4) void kern1n(const unsigned short* __restrict__ xh,
                                                 const unsigned short* __restrict__ W2h,
                                                 float* __restrict__ part1)
{
    const int tid = threadIdx.x;
    const int f  = tid & 31;
    const int og = tid >> 5;
    const int o0 = 2*og, o1 = o0 + 1;
    const int ch = blockIdx.x & (CH-1);
    const int pg = blockIdx.x >> 4;

    int xoff[8];
    #pragma unroll
    for (int p = 0; p < 8; ++p) xoff[p] = xbase_of(pg*8 + p);

    const uint4* W2h4 = (const uint4*)W2h;
    const int c0 = ch*CC;

    float acc0[8], acc1[8];
    #pragma unroll
    for (int p = 0; p < 8; ++p) { acc0[p] = 0.f; acc1[p] = 0.f; }

    #pragma unroll 1
    for (int cl = 0; cl < CC; ++cl) {
        const int c = c0 + cl;
        const int coff = coff_of(c);
        const uint4 w0 = W2h4[(size_t)(c*DO + o0)*F + f];
        const uint4 w1 = W2h4[(size_t)(c*DO + o1)*F + f];
        #pragma unroll
        for (int p = 0; p < 8; ++p) {
            const uint4 xv = *(const uint4*)(xh + xoff[p] + coff);
            acc0[p] = dot8h(w0, xv, acc0[p]);
            acc1[p] = dot8h(w1, xv, acc1[p]);
        }
    }
    #pragma unroll
    for (int p = 0; p < 8; ++p) {
        const size_t base = ((size_t)(ch*NPOS + pg*8 + p))*DO;
        part1[(base + o0)*F + f] = acc0[p];
        part1[(base + o1)*F + f] = acc1[p];
    }
}

__global__ __launch_bounds__(512) void kernO(const float* __restrict__ part1,
                                             float* __restrict__ out1)
{
    __shared__ float red[512];
    const int pos = blockIdx.x, tid = threadIdx.x;
    const int f = tid & 31, o = tid >> 5;

    float s = 0.f;
    #pragma unroll
    for (int k = 0; k < CH; ++k)
        s += part1[(size_t)(k*NPOS + pos)*512 + tid];
    s *= (1.f/32.f);

    red[tid] = s*s;
    __syncthreads();
    if (tid < 256) red[tid] += red[tid + 256];
    __syncthreads();
    if (tid < 128) red[tid] += red[tid + 128];
    __syncthreads();
    if (tid < 64)  red[tid] += red[tid + 64];
    __syncthreads();
    if (tid < 32) {
        const float sn = red[tid] + red[tid + 32];
        red[tid] = (sn/(1.f + sn)) * rsqrtf(sn + EPS);
    }
    __syncthreads();
    out1[(size_t)pos*512 + f*DO + o] = s * red[f];
}

__global__ __launch_bounds__(256) void kern2n(const unsigned short* __restrict__ xh,
                                              const unsigned short* __restrict__ W2h,
                                              const float* __restrict__ out1,
                                              float* __restrict__ part2)
{
    __shared__ float red[2][4][8][32];
    __shared__ float ccs[2][8][32];

    const int tid = threadIdx.x;
    const int f  = tid & 31;
    const int og = tid >> 5;
    const int o0 = 2*og, o1 = o0 + 1;
    const int wv = tid >> 6;
    const int half = (tid >> 5) & 1;
    const int ch = blockIdx.x & (CH-1);
    const int pg = blockIdx.x >> 4;

    int xoff[8];
    #pragma unroll
    for (int p = 0; p < 8; ++p) xoff[p] = xbase_of(pg*8 + p);

    float u0[8], u1[8];
    #pragma unroll
    for (int p = 0; p < 8; ++p) {
        const float* up = out1 + (size_t)(pg*8 + p)*512 + f*DO;
        u0[p] = up[o0];
        u1[p] = up[o1];
    }

    const uint4* W2h4 = (const uint4*)W2h;
    const int c0 = ch*CC;

    float acc0[8], acc1[8];
    #pragma unroll
    for (int p = 0; p < 8; ++p) { acc0[p] = 0.f; acc1[p] = 0.f; }

    #pragma unroll 1
    for (int cl = 0; cl < CC; ++cl) {
        const int c = c0 + cl;
        const int buf = cl & 1;
        const int coff = coff_of(c);
        const uint4 w0 = W2h4[(size_t)(c*DO + o0)*F + f];
        const uint4 w1 = W2h4[(size_t)(c*DO + o1)*F + f];

        float pred0[8], pred1[8];
        #pragma unroll
        for (int p = 0; p < 8; ++p) {
            const uint4 xv = *(const uint4*)(xh + xoff[p] + coff);
            pred0[p] = dot8h(w0, xv, 0.f);
            pred1[p] = dot8h(w1, xv, 0.f);
        }

        #pragma unroll
        for (int p = 0; p < 8; ++p) {
            float ap = pred0[p]*u0[p] + pred1[p]*u1[p];
            ap += __shfl_xor(ap, 32);
            if (half == 0) red[buf][wv][p][f] = ap;
        }
        __syncthreads();

        {
            const int p2 = tid >> 5, f2 = tid & 31;
            const float agr = red[buf][0][p2][f2] + red[buf][1][p2][f2]
                            + red[buf][2][p2][f2] + red[buf][3][p2][f2];
            float m = agr;
            m = fmaxf(m, __shfl_xor(m, 1));
            m = fmaxf(m, __shfl_xor(m, 2));
            m = fmaxf(m, __shfl_xor(m, 4));
            m = fmaxf(m, __shfl_xor(m, 8));
            m = fmaxf(m, __shfl_xor(m, 16));
            const float e = __expf(agr - m);
            float s = e;
            s += __shfl_xor(s, 1);
            s += __shfl_xor(s, 2);
            s += __shfl_xor(s, 4);
            s += __shfl_xor(s, 8);
            s += __shfl_xor(s, 16);
            ccs[buf][p2][f2] = e / s;
        }
        __syncthreads();

        #pragma unroll
        for (int p = 0; p < 8; ++p) {
            const float cv = ccs[buf][p][f];
            acc0[p] += cv*pred0[p];
            acc1[p] += cv*pred1[p];
        }
    }

    #pragma unroll
    for (int p = 0; p < 8; ++p) {
        const size_t base = ((size_t)(ch*NPOS + pg*8 + p))*DO;
        part2[(base + o0)*F + f] = acc0[p];
        part2[(base + o1)*F + f] = acc1[p];
    }
}

__global__ __launch_bounds__(256) void kern3(const float* __restrict__ part2,
                                             float* __restrict__ out)
{
    const int tid = threadIdx.x;
    const int f = tid & 31, p = tid >> 5;
    const int pos = blockIdx.x*8 + p;

    float cent[DO];
    #pragma unroll
    for (int o = 0; o < DO; ++o) cent[o] = 0.f;
    #pragma unroll 1
    for (int k = 0; k < CH; ++k) {
        const float* s = part2 + (size_t)(k*NPOS + pos)*512 + f;
        #pragma unroll
        for (int o = 0; o < DO; ++o) cent[o] += s[o*F];
    }
    float sn = 0.f;
    #pragma unroll
    for (int o = 0; o < DO; ++o) sn += cent[o]*cent[o];
    const float sc = (sn/(1.f + sn)) * rsqrtf(sn + EPS);
    float* dst = out + ((size_t)pos*F + f)*DO;
    #pragma unroll
    for (int o = 0; o < DO; ++o) dst[o] = cent[o]*sc;
}

// -------- fp32 single-kernel fallback (only if ws too small) -------------------
__device__ __forceinline__ float dot8(const float4* __restrict__ w,
                                      const float4 p0, const float4 p1) {
    float4 a = w[0], b = w[1];
    return a.x*p0.x + a.y*p0.y + a.z*p0.z + a.w*p0.w
         + b.x*p1.x + b.y*p1.y + b.z*p1.z + b.w*p1.w;
}

__global__ __launch_bounds__(256) void capsule_kernel_f32(
    const float* __restrict__ x, const float* __restrict__ Wt,
    float* __restrict__ out)
{
    __shared__ float patch[C*DI];
    __shared__ float cent[F*DO];
    __shared__ float out1[F*DO];
    __shared__ float agr[F*C];
    __shared__ float scale_s[F];

    const int tid = threadIdx.x;
    const int pos = blockIdx.x;
    const int b   = pos / (HO*WO);
    const int rem = pos % (HO*WO);
    const int ho  = rem / WO;
    const int wo  = rem % WO;

    #pragma unroll
    for (int slab = 0; slab < 9; ++slab) {
        const int kh = slab / 3, kw = slab % 3;
        const float* src = x + (((b*H_IN + ho + kh)*W_IN + (wo + kw))*FIN)*DI;
        patch[slab*256 + tid] = src[tid];
    }
    __syncthreads();

    const float4* pv = (const float4*)patch;

    {
        const int fo0 = tid, fo1 = tid + 256;
        const int f0 = fo0 >> 4, o0 = fo0 & 15;
        const int f1 = fo1 >> 4, o1 = fo1 & 15;
        float acc0 = 0.f, acc1 = 0.f;
        for (int c = 0; c < C; ++c) {
            const float4 p0 = pv[c*2], p1 = pv[c*2+1];
            acc0 += dot8((const float4*)(Wt + ((f0*C + c)*DO + o0)*DI), p0, p1);
            acc1 += dot8((const float4*)(Wt + ((f1*C + c)*DO + o1)*DI), p0, p1);
        }
        cent[fo0] = acc0 * (1.f/32.f);
        cent[fo1] = acc1 * (1.f/32.f);
    }
    __syncthreads();

    if (tid < F) {
        float sn = 0.f;
        #pragma unroll
        for (int o = 0; o < DO; ++o) { float v = cent[tid*DO + o]; sn += v*v; }
        const float sc = (sn/(1.f + sn)) * rsqrtf(sn + EPS);
        #pragma unroll
        for (int o = 0; o < DO; ++o) out1[tid*DO + o] = cent[tid*DO + o] * sc;
    }
    __syncthreads();

    #pragma unroll 1
    for (int r = 0; r < (F*C)/256; ++r) {
        const int pp = tid + 256*r;
        const int f = pp / C, c = pp % C;
        const float4* wrow = (const float4*)(Wt + (f*C + c)*DO*DI);
        const float4 p0 = pv[c*2], p1 = pv[c*2+1];
        float a = 0.f;
        #pragma unroll
        for (int o = 0; o < DO; ++o) a += dot8(wrow + o*2, p0, p1) * out1[f*DO + o];
        agr[pp] = a;
    }
    __syncthreads();

    for (int c = tid; c < C; c += 256) {
        float m = -1e30f;
        #pragma unroll
        for (int f = 0; f < F; ++f) m = fmaxf(m, agr[f*C + c]);
        float s = 0.f;
        #pragma unroll
        for (int f = 0; f < F; ++f) {
            const float e = __expf(agr[f*C + c] - m);
            agr[f*C + c] = e; s += e;
        }
        const float inv = 1.f / s;
        #pragma unroll
        for (int f = 0; f < F; ++f) agr[f*C + c] *= inv;
    }
    __syncthreads();

    {
        const int fo0 = tid, fo1 = tid + 256;
        const int f0 = fo0 >> 4, o0 = fo0 & 15;
        const int f1 = fo1 >> 4, o1 = fo1 & 15;
        float acc0 = 0.f, acc1 = 0.f;
        for (int c = 0; c < C; ++c) {
            const float4 p0 = pv[c*2], p1 = pv[c*2+1];
            acc0 += agr[f0*C + c] * dot8((const float4*)(Wt + ((f0*C + c)*DO + o0)*DI), p0, p1);
            acc1 += agr[f1*C + c] * dot8((const float4*)(Wt + ((f1*C + c)*DO + o1)*DI), p0, p1);
        }
        cent[fo0] = acc0;
        cent[fo1] = acc1;
    }
    __syncthreads();

    if (tid < F) {
        float sn = 0.f;
        #pragma unroll
        for (int o = 0; o < DO; ++o) { float v = cent[tid*DO + o]; sn += v*v; }
        scale_s[tid] = (sn/(1.f + sn)) * rsqrtf(sn + EPS);
    }
    __syncthreads();

    out[pos*(F*DO) + tid]       = cent[tid]       * scale_s[tid >> 4];
    out[pos*(F*DO) + tid + 256] = cent[tid + 256] * scale_s[(tid >> 4) + 16];
}

extern "C" void kernel_launch(void* const* d_in, const int* in_sizes, int n_in,
                              void* d_out, int out_size, void* d_ws, size_t ws_size,
                              hipStream_t stream) {
    const float* x  = (const float*)d_in[0];
    const float* Wt = (const float*)d_in[1];
    float* out = (float*)d_out;

    if (ws_size >= W2H_BYTES + XH_BYTES + PART_BYTES + OUT1_BYTES) {
        unsigned short* W2h = (unsigned short*)d_ws;
        unsigned short* xh  = (unsigned short*)((char*)d_ws + W2H_BYTES);
        float* part = (float*)((char*)d_ws + W2H_BYTES + XH_BYTES);
        float* out1 = (float*)((char*)d_ws + W2H_BYTES + XH_BYTES + PART_BYTES);

        void* args[] = { (void*)&Wt, (void*)&x, (void*)&W2h, (void*)&xh,
                         (void*)&part, (void*)&out1, (void*)&out };
        hipError_t e = hipLaunchCooperativeKernel((const void*)fusedk,
                                                  dim3(GRID), dim3(256),
                                                  args, 0, stream);
        if (e != hipSuccess) {
            // fallback: exact R15 five-kernel pipeline
            kernConv<<<WBLK + XBLK, 256, 0, stream>>>(Wt, W2h, x, xh);
            kern1n<<<GRID, 256, 0, stream>>>(xh, W2h, part);
            kernO<<<NPOS, 512, 0, stream>>>(part, out1);
            kern2n<<<GRID, 256, 0, stream>>>(xh, W2h, out1, part);
            kern3<<<NPOS/8, 256, 0, stream>>>(part, out);
        }
    } else {
        capsule_kernel_f32<<<NPOS, 256, 0, stream>>>(x, Wt, out);
    }
}

// Round 17
// 144.861 us; speedup vs baseline: 4.5433x; 4.5433x over previous
//
#include <hip/hip_runtime.h>

#define NB   4
#define H_IN 14
#define W_IN 14
#define FIN  32
#define DI   8
#define F    32
#define C    288   // 3*3*32
#define DO   16
#define HO   12
#define WO   12
#define NPOS (NB*HO*WO)   // 576
#define EPS  1e-7f

#define CH   16            // c-chunks
#define CC   (C/CH)        // 18
#define GP   4             // positions per block (R17: halved for 2x TLP)
#define GRID (CH*(NPOS/GP))// 2304 blocks

#define XELE  (NB*H_IN*W_IN*FIN*DI)            // 200,704
#define W2H_BYTES  ((size_t)F*C*DO*DI*2)       // 2,359,296
#define XH_BYTES   ((size_t)XELE*2)            // 401,408
#define CENT_BYTES ((size_t)NPOS*F*DO*4)       // 1,179,648
#define PART_BYTES ((size_t)CH*CENT_BYTES)     // 18,874,368 (part1; part2 aliases)
#define OUT1_BYTES CENT_BYTES

#define WBLK ((F*C*DO)/256)                    // 576 conversion blocks for W
#define XBLK ((XELE/4 + 255)/256)              // 196 conversion blocks for x

typedef _Float16 h2 __attribute__((ext_vector_type(2)));

__device__ __forceinline__ unsigned int pack2(float a, float b) {
    h2 v; v.x = (_Float16)a; v.y = (_Float16)b;
    return __builtin_bit_cast(unsigned int, v);
}

// 8-term fp16 dot with fp32 accumulate
__device__ __forceinline__ float dot8h(const uint4 w, const uint4 v, float acc) {
#if __has_builtin(__builtin_amdgcn_fdot2)
    acc = __builtin_amdgcn_fdot2(__builtin_bit_cast(h2, w.x), __builtin_bit_cast(h2, v.x), acc, false);
    acc = __builtin_amdgcn_fdot2(__builtin_bit_cast(h2, w.y), __builtin_bit_cast(h2, v.y), acc, false);
    acc = __builtin_amdgcn_fdot2(__builtin_bit_cast(h2, w.z), __builtin_bit_cast(h2, v.z), acc, false);
    acc = __builtin_amdgcn_fdot2(__builtin_bit_cast(h2, w.w), __builtin_bit_cast(h2, v.w), acc, false);
#else
    const h2 w0 = __builtin_bit_cast(h2, w.x), v0 = __builtin_bit_cast(h2, v.x);
    const h2 w1 = __builtin_bit_cast(h2, w.y), v1 = __builtin_bit_cast(h2, v.y);
    const h2 w2 = __builtin_bit_cast(h2, w.z), v2 = __builtin_bit_cast(h2, v.z);
    const h2 w3 = __builtin_bit_cast(h2, w.w), v3 = __builtin_bit_cast(h2, v.w);
    acc += (float)w0.x*(float)v0.x + (float)w0.y*(float)v0.y
         + (float)w1.x*(float)v1.x + (float)w1.y*(float)v1.y
         + (float)w2.x*(float)v2.x + (float)w2.y*(float)v2.y
         + (float)w3.x*(float)v3.x + (float)w3.y*(float)v3.y;
#endif
    return acc;
}

__device__ __forceinline__ int xbase_of(int pos) {
    const int b = pos/(HO*WO), rem = pos%(HO*WO), ho = rem/WO, wo = rem%WO;
    return ((b*H_IN + ho)*W_IN + wo)*FIN*DI;
}

__device__ __forceinline__ int coff_of(int c) {
    const int slab = c >> 5, fin = c & 31;
    const int kh = slab/3, kw = slab%3;
    return (kh*W_IN + kw)*FIN*DI + fin*DI;
}

// ---- fused conversion: W[f][c][o][i] fp32 -> W2h[c][o][f][i] fp16, x -> xh ----
__global__ __launch_bounds__(256) void kernConv(const float* __restrict__ Wt,
                                                unsigned short* __restrict__ W2h,
                                                const float* __restrict__ x,
                                                unsigned short* __restrict__ xh) {
    const int b = blockIdx.x;
    if (b < WBLK) {
        const int idx = b*256 + threadIdx.x;
        const int f = idx & 31, o = (idx >> 5) & 15, c = idx >> 9;
        const float* src = Wt + ((size_t)(f*C + c)*DO + o)*DI;
        const float4 a = *(const float4*)src;
        const float4 bb = *(const float4*)(src + 4);
        uint4 r;
        r.x = pack2(a.x, a.y);  r.y = pack2(a.z, a.w);
        r.z = pack2(bb.x, bb.y); r.w = pack2(bb.z, bb.w);
        ((uint4*)W2h)[idx] = r;
    } else {
        const int i = (b - WBLK)*256 + threadIdx.x;
        if (i < XELE/4) {
            const float4 v = ((const float4*)x)[i];
            uint2 o;
            o.x = pack2(v.x, v.y); o.y = pack2(v.z, v.w);
            ((uint2*)xh)[i] = o;
        }
    }
}

// ---- kern1: cent1 partials. thread=(f, o-pair), GP=4 positions; scalar x. ----
// writes part1[ch][pos][o][f] fp32
__global__ __launch_bounds__(256, 8) void kern1n(const unsigned short* __restrict__ xh,
                                                 const unsigned short* __restrict__ W2h,
                                                 float* __restrict__ part1)
{
    const int tid = threadIdx.x;
    const int f  = tid & 31;
    const int og = tid >> 5;          // 0..7
    const int o0 = 2*og, o1 = o0 + 1;
    const int ch = blockIdx.x & (CH-1);
    const int pg = blockIdx.x >> 4;   // 0..143

    int xoff[GP];                     // block-uniform -> SGPRs
    #pragma unroll
    for (int p = 0; p < GP; ++p) xoff[p] = xbase_of(pg*GP + p);

    const uint4* W2h4 = (const uint4*)W2h;
    const int c0 = ch*CC;

    float acc0[GP], acc1[GP];
    #pragma unroll
    for (int p = 0; p < GP; ++p) { acc0[p] = 0.f; acc1[p] = 0.f; }

    #pragma unroll 1
    for (int cl = 0; cl < CC; ++cl) {
        const int c = c0 + cl;
        const int coff = coff_of(c);
        const uint4 w0 = W2h4[(size_t)(c*DO + o0)*F + f];
        const uint4 w1 = W2h4[(size_t)(c*DO + o1)*F + f];
        #pragma unroll
        for (int p = 0; p < GP; ++p) {
            const uint4 xv = *(const uint4*)(xh + xoff[p] + coff);  // uniform
            acc0[p] = dot8h(w0, xv, acc0[p]);
            acc1[p] = dot8h(w1, xv, acc1[p]);
        }
    }
    #pragma unroll
    for (int p = 0; p < GP; ++p) {
        const size_t base = ((size_t)(ch*NPOS + pg*GP + p))*DO;
        part1[(base + o0)*F + f] = acc0[p];
        part1[(base + o1)*F + f] = acc1[p];
    }
}

// ---- kernO: out1[pos][f][o] = squash(sum_ch part1 / 32). (unchanged) ----------
__global__ __launch_bounds__(512) void kernO(const float* __restrict__ part1,
                                             float* __restrict__ out1)
{
    __shared__ float red[512];
    const int pos = blockIdx.x, tid = threadIdx.x;
    const int f = tid & 31, o = tid >> 5;

    float s = 0.f;
    #pragma unroll
    for (int k = 0; k < CH; ++k)
        s += part1[(size_t)(k*NPOS + pos)*512 + tid];
    s *= (1.f/32.f);

    red[tid] = s*s;
    __syncthreads();
    if (tid < 256) red[tid] += red[tid + 256];
    __syncthreads();
    if (tid < 128) red[tid] += red[tid + 128];
    __syncthreads();
    if (tid < 64)  red[tid] += red[tid + 64];
    __syncthreads();
    if (tid < 32) {
        const float sn = red[tid] + red[tid + 32];
        red[tid] = (sn/(1.f + sn)) * rsqrtf(sn + EPS);
    }
    __syncthreads();
    out1[(size_t)pos*512 + f*DO + o] = s * red[f];
}

// ---- kern2: thread=(f, o-pair), GP=4 positions; scalar x; LDS softmax. --------
// writes part2[ch][pos][o][f] fp32 (aliases part1)
__global__ __launch_bounds__(256, 8) void kern2n(const unsigned short* __restrict__ xh,
                                                 const unsigned short* __restrict__ W2h,
                                                 const float* __restrict__ out1,
                                                 float* __restrict__ part2)
{
    __shared__ float red[2][4][GP][32];  // 4 KB (dbuf)
    __shared__ float ccs[2][GP][32];     // 1 KB (dbuf)

    const int tid = threadIdx.x;
    const int f  = tid & 31;
    const int og = tid >> 5;            // 0..7
    const int o0 = 2*og, o1 = o0 + 1;
    const int wv = tid >> 6;            // wave 0..3
    const int half = (tid >> 5) & 1;    // og parity within wave
    const int ch = blockIdx.x & (CH-1);
    const int pg = blockIdx.x >> 4;     // 0..143

    int xoff[GP];                       // block-uniform -> SGPRs
    #pragma unroll
    for (int p = 0; p < GP; ++p) xoff[p] = xbase_of(pg*GP + p);

    // out1 values for (f, o0/o1) per position
    float u0[GP], u1[GP];
    #pragma unroll
    for (int p = 0; p < GP; ++p) {
        const float* up = out1 + (size_t)(pg*GP + p)*512 + f*DO;
        u0[p] = up[o0];
        u1[p] = up[o1];
    }

    const uint4* W2h4 = (const uint4*)W2h;
    const int c0 = ch*CC;

    float acc0[GP], acc1[GP];
    #pragma unroll
    for (int p = 0; p < GP; ++p) { acc0[p] = 0.f; acc1[p] = 0.f; }

    #pragma unroll 1
    for (int cl = 0; cl < CC; ++cl) {
        const int c = c0 + cl;
        const int buf = cl & 1;
        const int coff = coff_of(c);
        const uint4 w0 = W2h4[(size_t)(c*DO + o0)*F + f];
        const uint4 w1 = W2h4[(size_t)(c*DO + o1)*F + f];

        float pred0[GP], pred1[GP];
        #pragma unroll
        for (int p = 0; p < GP; ++p) {
            const uint4 xv = *(const uint4*)(xh + xoff[p] + coff);  // uniform
            pred0[p] = dot8h(w0, xv, 0.f);
            pred1[p] = dot8h(w1, xv, 0.f);
        }

        // agr partial over this thread's two o's; combine og-pairs via xor-32
        #pragma unroll
        for (int p = 0; p < GP; ++p) {
            float ap = pred0[p]*u0[p] + pred1[p]*u1[p];
            ap += __shfl_xor(ap, 32);
            if (half == 0) red[buf][wv][p][f] = ap;
        }
        __syncthreads();

        // remapped role: (p2, f2) for p2<GP; finish f-sum, softmax over f
        {
            const int p2 = tid >> 5, f2 = tid & 31;
            if (p2 < GP) {
                const float agr = red[buf][0][p2][f2] + red[buf][1][p2][f2]
                                + red[buf][2][p2][f2] + red[buf][3][p2][f2];
                float m = agr;
                m = fmaxf(m, __shfl_xor(m, 1));
                m = fmaxf(m, __shfl_xor(m, 2));
                m = fmaxf(m, __shfl_xor(m, 4));
                m = fmaxf(m, __shfl_xor(m, 8));
                m = fmaxf(m, __shfl_xor(m, 16));
                const float e = __expf(agr - m);
                float s = e;
                s += __shfl_xor(s, 1);
                s += __shfl_xor(s, 2);
                s += __shfl_xor(s, 4);
                s += __shfl_xor(s, 8);
                s += __shfl_xor(s, 16);
                ccs[buf][p2][f2] = e / s;
            }
        }
        __syncthreads();

        // back to (f, og): accumulate cent2
        #pragma unroll
        for (int p = 0; p < GP; ++p) {
            const float cv = ccs[buf][p][f];
            acc0[p] += cv*pred0[p];
            acc1[p] += cv*pred1[p];
        }
    }

    #pragma unroll
    for (int p = 0; p < GP; ++p) {
        const size_t base = ((size_t)(ch*NPOS + pg*GP + p))*DO;
        part2[(base + o0)*F + f] = acc0[p];
        part2[(base + o1)*F + f] = acc1[p];
    }
}

// ---- kern3: reduce cent2 partials ([ch][pos][o][f]), squash, store. -----------
__global__ __launch_bounds__(256) void kern3(const float* __restrict__ part2,
                                             float* __restrict__ out)
{
    const int tid = threadIdx.x;
    const int f = tid & 31, p = tid >> 5;
    const int pos = blockIdx.x*8 + p;

    float cent[DO];
    #pragma unroll
    for (int o = 0; o < DO; ++o) cent[o] = 0.f;
    #pragma unroll 1
    for (int k = 0; k < CH; ++k) {
        const float* s = part2 + (size_t)(k*NPOS + pos)*512 + f;
        #pragma unroll
        for (int o = 0; o < DO; ++o) cent[o] += s[o*F];
    }
    float sn = 0.f;
    #pragma unroll
    for (int o = 0; o < DO; ++o) sn += cent[o]*cent[o];
    const float sc = (sn/(1.f + sn)) * rsqrtf(sn + EPS);
    float* dst = out + ((size_t)pos*F + f)*DO;
    #pragma unroll
    for (int o = 0; o < DO; ++o) dst[o] = cent[o]*sc;
}

// -------- fp32 single-kernel fallback (only if ws too small) -------------------
__device__ __forceinline__ float dot8(const float4* __restrict__ w,
                                      const float4 p0, const float4 p1) {
    float4 a = w[0], b = w[1];
    return a.x*p0.x + a.y*p0.y + a.z*p0.z + a.w*p0.w
         + b.x*p1.x + b.y*p1.y + b.z*p1.z + b.w*p1.w;
}

__global__ __launch_bounds__(256) void capsule_kernel_f32(
    const float* __restrict__ x, const float* __restrict__ Wt,
    float* __restrict__ out)
{
    __shared__ float patch[C*DI];
    __shared__ float cent[F*DO];
    __shared__ float out1[F*DO];
    __shared__ float agr[F*C];
    __shared__ float scale_s[F];

    const int tid = threadIdx.x;
    const int pos = blockIdx.x;
    const int b   = pos / (HO*WO);
    const int rem = pos % (HO*WO);
    const int ho  = rem / WO;
    const int wo  = rem % WO;

    #pragma unroll
    for (int slab = 0; slab < 9; ++slab) {
        const int kh = slab / 3, kw = slab % 3;
        const float* src = x + (((b*H_IN + ho + kh)*W_IN + (wo + kw))*FIN)*DI;
        patch[slab*256 + tid] = src[tid];
    }
    __syncthreads();

    const float4* pv = (const float4*)patch;

    {
        const int fo0 = tid, fo1 = tid + 256;
        const int f0 = fo0 >> 4, o0 = fo0 & 15;
        const int f1 = fo1 >> 4, o1 = fo1 & 15;
        float acc0 = 0.f, acc1 = 0.f;
        for (int c = 0; c < C; ++c) {
            const float4 p0 = pv[c*2], p1 = pv[c*2+1];
            acc0 += dot8((const float4*)(Wt + ((f0*C + c)*DO + o0)*DI), p0, p1);
            acc1 += dot8((const float4*)(Wt + ((f1*C + c)*DO + o1)*DI), p0, p1);
        }
        cent[fo0] = acc0 * (1.f/32.f);
        cent[fo1] = acc1 * (1.f/32.f);
    }
    __syncthreads();

    if (tid < F) {
        float sn = 0.f;
        #pragma unroll
        for (int o = 0; o < DO; ++o) { float v = cent[tid*DO + o]; sn += v*v; }
        const float sc = (sn/(1.f + sn)) * rsqrtf(sn + EPS);
        #pragma unroll
        for (int o = 0; o < DO; ++o) out1[tid*DO + o] = cent[tid*DO + o] * sc;
    }
    __syncthreads();

    #pragma unroll 1
    for (int r = 0; r < (F*C)/256; ++r) {
        const int pp = tid + 256*r;
        const int f = pp / C, c = pp % C;
        const float4* wrow = (const float4*)(Wt + (f*C + c)*DO*DI);
        const float4 p0 = pv[c*2], p1 = pv[c*2+1];
        float a = 0.f;
        #pragma unroll
        for (int o = 0; o < DO; ++o) a += dot8(wrow + o*2, p0, p1) * out1[f*DO + o];
        agr[pp] = a;
    }
    __syncthreads();

    for (int c = tid; c < C; c += 256) {
        float m = -1e30f;
        #pragma unroll
        for (int f = 0; f < F; ++f) m = fmaxf(m, agr[f*C + c]);
        float s = 0.f;
        #pragma unroll
        for (int f = 0; f < F; ++f) {
            const float e = __expf(agr[f*C + c] - m);
            agr[f*C + c] = e; s += e;
        }
        const float inv = 1.f / s;
        #pragma unroll
        for (int f = 0; f < F; ++f) agr[f*C + c] *= inv;
    }
    __syncthreads();

    {
        const int fo0 = tid, fo1 = tid + 256;
        const int f0 = fo0 >> 4, o0 = fo0 & 15;
        const int f1 = fo1 >> 4, o1 = fo1 & 15;
        float acc0 = 0.f, acc1 = 0.f;
        for (int c = 0; c < C; ++c) {
            const float4 p0 = pv[c*2], p1 = pv[c*2+1];
            acc0 += agr[f0*C + c] * dot8((const float4*)(Wt + ((f0*C + c)*DO + o0)*DI), p0, p1);
            acc1 += agr[f1*C + c] * dot8((const float4*)(Wt + ((f1*C + c)*DO + o1)*DI), p0, p1);
        }
        cent[fo0] = acc0;
        cent[fo1] = acc1;
    }
    __syncthreads();

    if (tid < F) {
        float sn = 0.f;
        #pragma unroll
        for (int o = 0; o < DO; ++o) { float v = cent[tid*DO + o]; sn += v*v; }
        scale_s[tid] = (sn/(1.f + sn)) * rsqrtf(sn + EPS);
    }
    __syncthreads();

    out[pos*(F*DO) + tid]       = cent[tid]       * scale_s[tid >> 4];
    out[pos*(F*DO) + tid + 256] = cent[tid + 256] * scale_s[(tid >> 4) + 16];
}

extern "C" void kernel_launch(void* const* d_in, const int* in_sizes, int n_in,
                              void* d_out, int out_size, void* d_ws, size_t ws_size,
                              hipStream_t stream) {
    const float* x  = (const float*)d_in[0];
    const float* Wt = (const float*)d_in[1];
    float* out = (float*)d_out;

    if (ws_size >= W2H_BYTES + XH_BYTES + PART_BYTES + OUT1_BYTES) {
        unsigned short* W2h = (unsigned short*)d_ws;
        unsigned short* xh  = (unsigned short*)((char*)d_ws + W2H_BYTES);
        float* part = (float*)((char*)d_ws + W2H_BYTES + XH_BYTES);   // part2 aliases
        float* out1 = (float*)((char*)d_ws + W2H_BYTES + XH_BYTES + PART_BYTES);
        kernConv<<<WBLK + XBLK, 256, 0, stream>>>(Wt, W2h, x, xh);    // 772 blocks
        kern1n<<<GRID, 256, 0, stream>>>(xh, W2h, part);              // 2304 blocks
        kernO<<<NPOS, 512, 0, stream>>>(part, out1);                  // 576 blocks
        kern2n<<<GRID, 256, 0, stream>>>(xh, W2h, out1, part);        // 2304 blocks
        kern3<<<NPOS/8, 256, 0, stream>>>(part, out);                 // 72 blocks
    } else {
        capsule_kernel_f32<<<NPOS, 256, 0, stream>>>(x, Wt, out);
    }
}

// Round 18
// 138.119 us; speedup vs baseline: 4.7650x; 1.0488x over previous
//
#include <hip/hip_runtime.h>

#define NB   4
#define H_IN 14
#define W_IN 14
#define FIN  32
#define DI   8
#define F    32
#define C    288   // 3*3*32
#define DO   16
#define HO   12
#define WO   12
#define NPOS (NB*HO*WO)   // 576
#define EPS  1e-7f

#define CH   16            // c-chunks (kern2)
#define CC   (C/CH)        // 18
#define GP   8             // positions per block in kern2 (R15-proven)
#define GRID (CH*(NPOS/GP))// 1152

#define KTOT (C*DI)        // 2304 = K of the cent1 GEMM

#define W2H_BYTES  ((size_t)F*C*DO*DI*2)       // 2,359,296  (transposed, kern2)
#define WH_BYTES   ((size_t)F*C*DO*DI*2)       // 2,359,296  (orig layout, MFMA B)
#define PH_BYTES   ((size_t)NPOS*KTOT*2)       // 2,654,208  (patch matrix fp16)
#define PART_BYTES ((size_t)CH*NPOS*F*DO*4)    // 18,874,368 (part2)
#define OUT1_BYTES ((size_t)NPOS*F*DO*4)       // 1,179,648

#define CVT_W2H 576
#define CVT_WH  576        // 147456 uint4
#define CVT_PH  648        // 165888 uint4
#define CVT_GRID (CVT_W2H + CVT_WH + CVT_PH)

typedef _Float16 h2 __attribute__((ext_vector_type(2)));
typedef _Float16 h8v __attribute__((ext_vector_type(8)));
typedef float    f4v __attribute__((ext_vector_type(4)));

__device__ __forceinline__ unsigned int pack2(float a, float b) {
    h2 v; v.x = (_Float16)a; v.y = (_Float16)b;
    return __builtin_bit_cast(unsigned int, v);
}

// 8-term fp16 dot with fp32 accumulate
__device__ __forceinline__ float dot8h(const uint4 w, const uint4 v, float acc) {
#if __has_builtin(__builtin_amdgcn_fdot2)
    acc = __builtin_amdgcn_fdot2(__builtin_bit_cast(h2, w.x), __builtin_bit_cast(h2, v.x), acc, false);
    acc = __builtin_amdgcn_fdot2(__builtin_bit_cast(h2, w.y), __builtin_bit_cast(h2, v.y), acc, false);
    acc = __builtin_amdgcn_fdot2(__builtin_bit_cast(h2, w.z), __builtin_bit_cast(h2, v.z), acc, false);
    acc = __builtin_amdgcn_fdot2(__builtin_bit_cast(h2, w.w), __builtin_bit_cast(h2, v.w), acc, false);
#else
    const h2 w0 = __builtin_bit_cast(h2, w.x), v0 = __builtin_bit_cast(h2, v.x);
    const h2 w1 = __builtin_bit_cast(h2, w.y), v1 = __builtin_bit_cast(h2, v.y);
    const h2 w2 = __builtin_bit_cast(h2, w.z), v2 = __builtin_bit_cast(h2, v.z);
    const h2 w3 = __builtin_bit_cast(h2, w.w), v3 = __builtin_bit_cast(h2, v.w);
    acc += (float)w0.x*(float)v0.x + (float)w0.y*(float)v0.y
         + (float)w1.x*(float)v1.x + (float)w1.y*(float)v1.y
         + (float)w2.x*(float)v2.x + (float)w2.y*(float)v2.y
         + (float)w3.x*(float)v3.x + (float)w3.y*(float)v3.y;
#endif
    return acc;
}

__device__ __forceinline__ int xbase_of(int pos) {
    const int b = pos/(HO*WO), rem = pos%(HO*WO), ho = rem/WO, wo = rem%WO;
    return ((b*H_IN + ho)*W_IN + wo)*FIN*DI;
}

__device__ __forceinline__ int coff_of(int c) {
    const int slab = c >> 5, fin = c & 31;
    const int kh = slab/3, kw = slab%3;
    return (kh*W_IN + kw)*FIN*DI + fin*DI;
}

// ---- conversion: W2h (transposed, kern2), Wh (orig layout fp16, MFMA B),
// ---- Ph (patch matrix [pos][c*8+i] fp16, MFMA A + kern2 x)
__global__ __launch_bounds__(256) void kernConv(const float* __restrict__ Wt,
                                                const float* __restrict__ x,
                                                unsigned short* __restrict__ W2h,
                                                unsigned short* __restrict__ Wh,
                                                unsigned short* __restrict__ Ph) {
    const int b = blockIdx.x;
    if (b < CVT_W2H) {                 // W2h[c][o][f][i] <- W[f][c][o][i]
        const int idx = b*256 + threadIdx.x;       // (c*DO+o)*F+f
        const int f = idx & 31, o = (idx >> 5) & 15, c = idx >> 9;
        const float* src = Wt + ((size_t)(f*C + c)*DO + o)*DI;
        const float4 a = *(const float4*)src;
        const float4 bb = *(const float4*)(src + 4);
        uint4 r;
        r.x = pack2(a.x, a.y);   r.y = pack2(a.z, a.w);
        r.z = pack2(bb.x, bb.y); r.w = pack2(bb.z, bb.w);
        ((uint4*)W2h)[idx] = r;
    } else if (b < CVT_W2H + CVT_WH) { // Wh = fp16(Wt), same layout
        const int idx = (b - CVT_W2H)*256 + threadIdx.x;   // 147456
        const float* src = Wt + (size_t)idx*8;
        const float4 a = *(const float4*)src;
        const float4 bb = *(const float4*)(src + 4);
        uint4 r;
        r.x = pack2(a.x, a.y);   r.y = pack2(a.z, a.w);
        r.z = pack2(bb.x, bb.y); r.w = pack2(bb.z, bb.w);
        ((uint4*)Wh)[idx] = r;
    } else {                           // Ph[pos][c*8+i]
        const int pc = (b - CVT_W2H - CVT_WH)*256 + threadIdx.x;  // 165888
        const int pos = pc / C, c = pc % C;
        const float* src = x + xbase_of(pos) + coff_of(c);
        const float4 a = *(const float4*)src;
        const float4 bb = *(const float4*)(src + 4);
        uint4 r;
        r.x = pack2(a.x, a.y);   r.y = pack2(a.z, a.w);
        r.z = pack2(bb.x, bb.y); r.w = pack2(bb.z, bb.w);
        ((uint4*)Ph)[pc] = r;
    }
}

// ---- kernM1: cent1 GEMM via MFMA + fused squash -> out1. ----------------------
// Per wave: one f, one 16-pos tile. C[m=pos][n=o] = P[16,2304] x W[f][2304,16].
// A-frag: lane(m=lane&15, q=lane>>4) holds P[pos0+m][s*32 + q*8 + j], j=0..7.
// B-frag: lane(n=lane&15, q) holds W[f][c=s*4+q][o=n][i=j] (contiguous uint4).
// D: lane holds D[m=q*4+r][n=lane&15], r=0..3.
__global__ __launch_bounds__(256) void kernM1(const unsigned short* __restrict__ Ph,
                                              const unsigned short* __restrict__ Wh,
                                              float* __restrict__ out1)
{
    const int lane = threadIdx.x & 63;
    const int wv   = threadIdx.x >> 6;
    const int f    = blockIdx.x & 31;
    const int pt   = (blockIdx.x >> 5)*4 + wv;    // 0..35
    const int pos0 = pt*16;
    const int n    = lane & 15, q = lane >> 4;

    const unsigned short* pa = Ph + (size_t)(pos0 + n)*KTOT + q*8;   // A: m = lane&15
    const unsigned short* pb = Wh + ((size_t)(f*C + q)*DO + n)*DI;   // B: n = lane&15

    f4v acc0 = {0.f,0.f,0.f,0.f}, acc1 = {0.f,0.f,0.f,0.f};
    #pragma unroll 4
    for (int s = 0; s < KTOT/32; s += 2) {        // 72 steps, 2 chains
        const h8v a0 = *(const h8v*)(pa + (size_t)s*32);
        const h8v b0 = *(const h8v*)(pb + (size_t)s*4*DO*DI);
        const h8v a1 = *(const h8v*)(pa + (size_t)(s+1)*32);
        const h8v b1 = *(const h8v*)(pb + (size_t)(s+1)*4*DO*DI);
        acc0 = __builtin_amdgcn_mfma_f32_16x16x32_f16(a0, b0, acc0, 0, 0, 0);
        acc1 = __builtin_amdgcn_mfma_f32_16x16x32_f16(a1, b1, acc1, 0, 0, 0);
    }

    // epilogue: cent1 = D/32; squash over o (= lanes within each 16-group)
    #pragma unroll
    for (int r = 0; r < 4; ++r) {
        const float v = (acc0[r] + acc1[r]) * (1.f/32.f);
        float sq = v*v;
        sq += __shfl_xor(sq, 1);
        sq += __shfl_xor(sq, 2);
        sq += __shfl_xor(sq, 4);
        sq += __shfl_xor(sq, 8);
        const float sc = (sq/(1.f + sq)) * rsqrtf(sq + EPS);
        out1[(size_t)(pos0 + q*4 + r)*512 + f*DO + n] = v * sc;
    }
}

// ---- kern2: R15-proven body; x from Ph (block-uniform scalar loads). ----------
// writes part2[ch][pos][o][f] fp32
__global__ __launch_bounds__(256) void kern2n(const unsigned short* __restrict__ Ph,
                                              const unsigned short* __restrict__ W2h,
                                              const float* __restrict__ out1,
                                              float* __restrict__ part2)
{
    __shared__ float red[2][4][GP][32];  // 8 KB (dbuf)
    __shared__ float ccs[2][GP][32];     // 2 KB (dbuf)

    const int tid = threadIdx.x;
    const int f  = tid & 31;
    const int og = tid >> 5;            // 0..7
    const int o0 = 2*og, o1 = o0 + 1;
    const int wv = tid >> 6;            // wave 0..3
    const int half = (tid >> 5) & 1;    // og parity within wave
    const int ch = blockIdx.x & (CH-1);
    const int pg = blockIdx.x >> 4;     // 0..71

    int poff[GP];                       // block-uniform -> SGPRs
    #pragma unroll
    for (int p = 0; p < GP; ++p) poff[p] = (pg*GP + p)*KTOT;

    float u0[GP], u1[GP];
    #pragma unroll
    for (int p = 0; p < GP; ++p) {
        const float* up = out1 + (size_t)(pg*GP + p)*512 + f*DO;
        u0[p] = up[o0];
        u1[p] = up[o1];
    }

    const uint4* W2h4 = (const uint4*)W2h;
    const int c0 = ch*CC;

    float acc0[GP], acc1[GP];
    #pragma unroll
    for (int p = 0; p < GP; ++p) { acc0[p] = 0.f; acc1[p] = 0.f; }

    #pragma unroll 1
    for (int cl = 0; cl < CC; ++cl) {
        const int c = c0 + cl;
        const int buf = cl & 1;
        const uint4 w0 = W2h4[(size_t)(c*DO + o0)*F + f];
        const uint4 w1 = W2h4[(size_t)(c*DO + o1)*F + f];

        float pred0[GP], pred1[GP];
        #pragma unroll
        for (int p = 0; p < GP; ++p) {
            const uint4 xv = *(const uint4*)(Ph + poff[p] + c*DI);  // uniform
            pred0[p] = dot8h(w0, xv, 0.f);
            pred1[p] = dot8h(w1, xv, 0.f);
        }

        // agr partial over this thread's two o's; combine og-pairs via xor-32
        #pragma unroll
        for (int p = 0; p < GP; ++p) {
            float ap = pred0[p]*u0[p] + pred1[p]*u1[p];
            ap += __shfl_xor(ap, 32);
            if (half == 0) red[buf][wv][p][f] = ap;
        }
        __syncthreads();

        // remapped role: (p2, f2); finish f-sum, softmax over f, publish cc
        {
            const int p2 = tid >> 5, f2 = tid & 31;
            const float agr = red[buf][0][p2][f2] + red[buf][1][p2][f2]
                            + red[buf][2][p2][f2] + red[buf][3][p2][f2];
            float m = agr;
            m = fmaxf(m, __shfl_xor(m, 1));
            m = fmaxf(m, __shfl_xor(m, 2));
            m = fmaxf(m, __shfl_xor(m, 4));
            m = fmaxf(m, __shfl_xor(m, 8));
            m = fmaxf(m, __shfl_xor(m, 16));
            const float e = __expf(agr - m);
            float s = e;
            s += __shfl_xor(s, 1);
            s += __shfl_xor(s, 2);
            s += __shfl_xor(s, 4);
            s += __shfl_xor(s, 8);
            s += __shfl_xor(s, 16);
            ccs[buf][p2][f2] = e / s;
        }
        __syncthreads();

        // back to (f, og): accumulate cent2
        #pragma unroll
        for (int p = 0; p < GP; ++p) {
            const float cv = ccs[buf][p][f];
            acc0[p] += cv*pred0[p];
            acc1[p] += cv*pred1[p];
        }
    }

    #pragma unroll
    for (int p = 0; p < GP; ++p) {
        const size_t base = ((size_t)(ch*NPOS + pg*GP + p))*DO;
        part2[(base + o0)*F + f] = acc0[p];
        part2[(base + o1)*F + f] = acc1[p];
    }
}

// ---- kern3: reduce cent2 partials ([ch][pos][o][f]), squash, store. -----------
__global__ __launch_bounds__(256) void kern3(const float* __restrict__ part2,
                                             float* __restrict__ out)
{
    const int tid = threadIdx.x;
    const int f = tid & 31, p = tid >> 5;
    const int pos = blockIdx.x*8 + p;

    float cent[DO];
    #pragma unroll
    for (int o = 0; o < DO; ++o) cent[o] = 0.f;
    #pragma unroll 1
    for (int k = 0; k < CH; ++k) {
        const float* s = part2 + (size_t)(k*NPOS + pos)*512 + f;
        #pragma unroll
        for (int o = 0; o < DO; ++o) cent[o] += s[o*F];
    }
    float sn = 0.f;
    #pragma unroll
    for (int o = 0; o < DO; ++o) sn += cent[o]*cent[o];
    const float sc = (sn/(1.f + sn)) * rsqrtf(sn + EPS);
    float* dst = out + ((size_t)pos*F + f)*DO;
    #pragma unroll
    for (int o = 0; o < DO; ++o) dst[o] = cent[o]*sc;
}

// -------- fp32 single-kernel fallback (only if ws too small) -------------------
__device__ __forceinline__ float dot8(const float4* __restrict__ w,
                                      const float4 p0, const float4 p1) {
    float4 a = w[0], b = w[1];
    return a.x*p0.x + a.y*p0.y + a.z*p0.z + a.w*p0.w
         + b.x*p1.x + b.y*p1.y + b.z*p1.z + b.w*p1.w;
}

__global__ __launch_bounds__(256) void capsule_kernel_f32(
    const float* __restrict__ x, const float* __restrict__ Wt,
    float* __restrict__ out)
{
    __shared__ float patch[C*DI];
    __shared__ float cent[F*DO];
    __shared__ float out1[F*DO];
    __shared__ float agr[F*C];
    __shared__ float scale_s[F];

    const int tid = threadIdx.x;
    const int pos = blockIdx.x;
    const int b   = pos / (HO*WO);
    const int rem = pos % (HO*WO);
    const int ho  = rem / WO;
    const int wo  = rem % WO;

    #pragma unroll
    for (int slab = 0; slab < 9; ++slab) {
        const int kh = slab / 3, kw = slab % 3;
        const float* src = x + (((b*H_IN + ho + kh)*W_IN + (wo + kw))*FIN)*DI;
        patch[slab*256 + tid] = src[tid];
    }
    __syncthreads();

    const float4* pv = (const float4*)patch;

    {
        const int fo0 = tid, fo1 = tid + 256;
        const int f0 = fo0 >> 4, o0 = fo0 & 15;
        const int f1 = fo1 >> 4, o1 = fo1 & 15;
        float acc0 = 0.f, acc1 = 0.f;
        for (int c = 0; c < C; ++c) {
            const float4 p0 = pv[c*2], p1 = pv[c*2+1];
            acc0 += dot8((const float4*)(Wt + ((f0*C + c)*DO + o0)*DI), p0, p1);
            acc1 += dot8((const float4*)(Wt + ((f1*C + c)*DO + o1)*DI), p0, p1);
        }
        cent[fo0] = acc0 * (1.f/32.f);
        cent[fo1] = acc1 * (1.f/32.f);
    }
    __syncthreads();

    if (tid < F) {
        float sn = 0.f;
        #pragma unroll
        for (int o = 0; o < DO; ++o) { float v = cent[tid*DO + o]; sn += v*v; }
        const float sc = (sn/(1.f + sn)) * rsqrtf(sn + EPS);
        #pragma unroll
        for (int o = 0; o < DO; ++o) out1[tid*DO + o] = cent[tid*DO + o] * sc;
    }
    __syncthreads();

    #pragma unroll 1
    for (int r = 0; r < (F*C)/256; ++r) {
        const int pp = tid + 256*r;
        const int f = pp / C, c = pp % C;
        const float4* wrow = (const float4*)(Wt + (f*C + c)*DO*DI);
        const float4 p0 = pv[c*2], p1 = pv[c*2+1];
        float a = 0.f;
        #pragma unroll
        for (int o = 0; o < DO; ++o) a += dot8(wrow + o*2, p0, p1) * out1[f*DO + o];
        agr[pp] = a;
    }
    __syncthreads();

    for (int c = tid; c < C; c += 256) {
        float m = -1e30f;
        #pragma unroll
        for (int f = 0; f < F; ++f) m = fmaxf(m, agr[f*C + c]);
        float s = 0.f;
        #pragma unroll
        for (int f = 0; f < F; ++f) {
            const float e = __expf(agr[f*C + c] - m);
            agr[f*C + c] = e; s += e;
        }
        const float inv = 1.f / s;
        #pragma unroll
        for (int f = 0; f < F; ++f) agr[f*C + c] *= inv;
    }
    __syncthreads();

    {
        const int fo0 = tid, fo1 = tid + 256;
        const int f0 = fo0 >> 4, o0 = fo0 & 15;
        const int f1 = fo1 >> 4, o1 = fo1 & 15;
        float acc0 = 0.f, acc1 = 0.f;
        for (int c = 0; c < C; ++c) {
            const float4 p0 = pv[c*2], p1 = pv[c*2+1];
            acc0 += agr[f0*C + c] * dot8((const float4*)(Wt + ((f0*C + c)*DO + o0)*DI), p0, p1);
            acc1 += agr[f1*C + c] * dot8((const float4*)(Wt + ((f1*C + c)*DO + o1)*DI), p0, p1);
        }
        cent[fo0] = acc0;
        cent[fo1] = acc1;
    }
    __syncthreads();

    if (tid < F) {
        float sn = 0.f;
        #pragma unroll
        for (int o = 0; o < DO; ++o) { float v = cent[tid*DO + o]; sn += v*v; }
        scale_s[tid] = (sn/(1.f + sn)) * rsqrtf(sn + EPS);
    }
    __syncthreads();

    out[pos*(F*DO) + tid]       = cent[tid]       * scale_s[tid >> 4];
    out[pos*(F*DO) + tid + 256] = cent[tid + 256] * scale_s[(tid >> 4) + 16];
}

extern "C" void kernel_launch(void* const* d_in, const int* in_sizes, int n_in,
                              void* d_out, int out_size, void* d_ws, size_t ws_size,
                              hipStream_t stream) {
    const float* x  = (const float*)d_in[0];
    const float* Wt = (const float*)d_in[1];
    float* out = (float*)d_out;

    if (ws_size >= W2H_BYTES + WH_BYTES + PH_BYTES + PART_BYTES + OUT1_BYTES) {
        char* p = (char*)d_ws;
        unsigned short* W2h = (unsigned short*)p;            p += W2H_BYTES;
        unsigned short* Wh  = (unsigned short*)p;            p += WH_BYTES;
        unsigned short* Ph  = (unsigned short*)p;            p += PH_BYTES;
        float* part = (float*)p;                             p += PART_BYTES;
        float* out1 = (float*)p;

        kernConv<<<CVT_GRID, 256, 0, stream>>>(Wt, x, W2h, Wh, Ph);  // 1800 blocks
        kernM1<<<(F/1)*9, 256, 0, stream>>>(Ph, Wh, out1);           // 288 blocks
        kern2n<<<GRID, 256, 0, stream>>>(Ph, W2h, out1, part);       // 1152 blocks
        kern3<<<NPOS/8, 256, 0, stream>>>(part, out);                // 72 blocks
    } else {
        capsule_kernel_f32<<<NPOS, 256, 0, stream>>>(x, Wt, out);
    }
}

// Round 19
// 133.618 us; speedup vs baseline: 4.9255x; 1.0337x over previous
//
#include <hip/hip_runtime.h>

#define NB   4
#define H_IN 14
#define W_IN 14
#define FIN  32
#define DI   8
#define F    32
#define C    288   // 3*3*32
#define DO   16
#define HO   12
#define WO   12
#define NPOS (NB*HO*WO)   // 576
#define EPS  1e-7f

#define CH   16            // c-chunks (kern2)
#define CC   (C/CH)        // 18
#define GP   8             // positions per block in kern2 (R15-proven)
#define GRID (CH*(NPOS/GP))// 1152

#define KTOT (C*DI)        // 2304 = K of the cent1 GEMM
#define KPAD 2312          // LDS row pad: 1156 words % 32 = 4 -> conflict-free

#define W2H_BYTES  ((size_t)F*C*DO*DI*2)       // 2,359,296  (transposed, kern2)
#define WH_BYTES   ((size_t)F*C*DO*DI*2)       // 2,359,296  (orig layout, MFMA B)
#define PH_BYTES   ((size_t)NPOS*KTOT*2)       // 2,654,208  (patch matrix fp16)
#define PART_BYTES ((size_t)CH*NPOS*F*DO*4)    // 18,874,368 (part2)
#define OUT1_BYTES ((size_t)NPOS*F*DO*4)       // 1,179,648

#define CVT_W2H 576
#define CVT_WH  576        // 147456 uint4
#define CVT_PH  648        // 165888 uint4
#define CVT_GRID (CVT_W2H + CVT_WH + CVT_PH)

typedef _Float16 h2 __attribute__((ext_vector_type(2)));
typedef _Float16 h8v __attribute__((ext_vector_type(8)));
typedef float    f4v __attribute__((ext_vector_type(4)));

__device__ __forceinline__ unsigned int pack2(float a, float b) {
    h2 v; v.x = (_Float16)a; v.y = (_Float16)b;
    return __builtin_bit_cast(unsigned int, v);
}

// 8-term fp16 dot with fp32 accumulate
__device__ __forceinline__ float dot8h(const uint4 w, const uint4 v, float acc) {
#if __has_builtin(__builtin_amdgcn_fdot2)
    acc = __builtin_amdgcn_fdot2(__builtin_bit_cast(h2, w.x), __builtin_bit_cast(h2, v.x), acc, false);
    acc = __builtin_amdgcn_fdot2(__builtin_bit_cast(h2, w.y), __builtin_bit_cast(h2, v.y), acc, false);
    acc = __builtin_amdgcn_fdot2(__builtin_bit_cast(h2, w.z), __builtin_bit_cast(h2, v.z), acc, false);
    acc = __builtin_amdgcn_fdot2(__builtin_bit_cast(h2, w.w), __builtin_bit_cast(h2, v.w), acc, false);
#else
    const h2 w0 = __builtin_bit_cast(h2, w.x), v0 = __builtin_bit_cast(h2, v.x);
    const h2 w1 = __builtin_bit_cast(h2, w.y), v1 = __builtin_bit_cast(h2, v.y);
    const h2 w2 = __builtin_bit_cast(h2, w.z), v2 = __builtin_bit_cast(h2, v.z);
    const h2 w3 = __builtin_bit_cast(h2, w.w), v3 = __builtin_bit_cast(h2, v.w);
    acc += (float)w0.x*(float)v0.x + (float)w0.y*(float)v0.y
         + (float)w1.x*(float)v1.x + (float)w1.y*(float)v1.y
         + (float)w2.x*(float)v2.x + (float)w2.y*(float)v2.y
         + (float)w3.x*(float)v3.x + (float)w3.y*(float)v3.y;
#endif
    return acc;
}

__device__ __forceinline__ int xbase_of(int pos) {
    const int b = pos/(HO*WO), rem = pos%(HO*WO), ho = rem/WO, wo = rem%WO;
    return ((b*H_IN + ho)*W_IN + wo)*FIN*DI;
}

__device__ __forceinline__ int coff_of(int c) {
    const int slab = c >> 5, fin = c & 31;
    const int kh = slab/3, kw = slab%3;
    return (kh*W_IN + kw)*FIN*DI + fin*DI;
}

// ---- conversion (coalesced READS everywhere; scattered writes absorbed by L2)
__global__ __launch_bounds__(256) void kernConv(const float* __restrict__ Wt,
                                                const float* __restrict__ x,
                                                unsigned short* __restrict__ W2h,
                                                unsigned short* __restrict__ Wh,
                                                unsigned short* __restrict__ Ph) {
    const int b = blockIdx.x;
    if (b < CVT_W2H) {                 // W2h[c][o][f][i] <- W[f][c][o][i]
        const int idx = b*256 + threadIdx.x;       // linear over Wt rows (f*C+c)*DO+o
        const float* src = Wt + (size_t)idx*8;     // coalesced read
        const float4 a = *(const float4*)src;
        const float4 bb = *(const float4*)(src + 4);
        uint4 r;
        r.x = pack2(a.x, a.y);   r.y = pack2(a.z, a.w);
        r.z = pack2(bb.x, bb.y); r.w = pack2(bb.z, bb.w);
        const int o = idx & 15;
        const int c = (idx >> 4) % C;
        const int f = idx / (C*DO);
        ((uint4*)W2h)[(size_t)(c*DO + o)*F + f] = r;   // scattered write
    } else if (b < CVT_W2H + CVT_WH) { // Wh = fp16(Wt), same layout (copy-convert)
        const int idx = (b - CVT_W2H)*256 + threadIdx.x;   // 147456
        const float* src = Wt + (size_t)idx*8;
        const float4 a = *(const float4*)src;
        const float4 bb = *(const float4*)(src + 4);
        uint4 r;
        r.x = pack2(a.x, a.y);   r.y = pack2(a.z, a.w);
        r.z = pack2(bb.x, bb.y); r.w = pack2(bb.z, bb.w);
        ((uint4*)Wh)[idx] = r;
    } else {                           // Ph[pos][c*8+i]
        const int pc = (b - CVT_W2H - CVT_WH)*256 + threadIdx.x;  // 165888
        const int pos = pc / C, c = pc % C;
        const float* src = x + xbase_of(pos) + coff_of(c);
        const float4 a = *(const float4*)src;
        const float4 bb = *(const float4*)(src + 4);
        uint4 r;
        r.x = pack2(a.x, a.y);   r.y = pack2(a.z, a.w);
        r.z = pack2(bb.x, bb.y); r.w = pack2(bb.z, bb.w);
        ((uint4*)Ph)[pc] = r;
    }
}

// ---- kernM1: cent1 GEMM via MFMA + fused squash -> out1. ----------------------
// Block = (pos-tile pt, f-group fg); A-tile staged in LDS coalesced, shared by
// all 4 waves (f = wv*8 + fg). Per wave: C[m=pos][n=o] = P[16,2304] x W[f][.,16].
// A-frag: lane(m=lane&15, q=lane>>4) holds P[pos0+m][s*32 + q*8 + j], j=0..7.
// B-frag: lane(n=lane&15, q) holds W[f][c=s*4+q][o=n][i=j] (contiguous uint4).
// D: lane holds D[m=q*4+r][n=lane&15], r=0..3.
__global__ __launch_bounds__(256) void kernM1(const unsigned short* __restrict__ Ph,
                                              const unsigned short* __restrict__ Wh,
                                              float* __restrict__ out1)
{
    __shared__ unsigned short As[16][KPAD];       // 73,984 B

    const int tid  = threadIdx.x;
    const int lane = tid & 63;
    const int wv   = tid >> 6;
    const int pt   = blockIdx.x >> 3;             // 0..35
    const int fg   = blockIdx.x & 7;              // 0..7
    const int f    = wv*8 + fg;                   // all 32 f covered
    const int pos0 = pt*16;
    const int n    = lane & 15, q = lane >> 4;

    // stage A-tile: 4608 uint4, coalesced (row = linear/288, col8 = linear%288)
    #pragma unroll
    for (int r = 0; r < 18; ++r) {
        const int linear = r*256 + tid;
        const int row = linear / 288, col8 = linear % 288;
        const uint4 v = *(const uint4*)(Ph + (size_t)(pos0 + row)*KTOT + col8*8);
        *(uint4*)&As[row][col8*8] = v;
    }
    __syncthreads();

    const unsigned short* pa = &As[n][q*8];                          // A: m = lane&15
    const unsigned short* pb = Wh + ((size_t)(f*C + q)*DO + n)*DI;   // B: n = lane&15

    f4v acc0 = {0.f,0.f,0.f,0.f}, acc1 = {0.f,0.f,0.f,0.f};
    #pragma unroll 4
    for (int s = 0; s < KTOT/32; s += 2) {        // 72 steps, 2 chains
        const h8v a0 = *(const h8v*)(pa + s*32);
        const h8v b0 = *(const h8v*)(pb + (size_t)s*4*DO*DI);
        const h8v a1 = *(const h8v*)(pa + (s+1)*32);
        const h8v b1 = *(const h8v*)(pb + (size_t)(s+1)*4*DO*DI);
        acc0 = __builtin_amdgcn_mfma_f32_16x16x32_f16(a0, b0, acc0, 0, 0, 0);
        acc1 = __builtin_amdgcn_mfma_f32_16x16x32_f16(a1, b1, acc1, 0, 0, 0);
    }

    // epilogue: cent1 = D/32; squash over o (= lanes within each 16-group)
    #pragma unroll
    for (int r = 0; r < 4; ++r) {
        const float v = (acc0[r] + acc1[r]) * (1.f/32.f);
        float sq = v*v;
        sq += __shfl_xor(sq, 1);
        sq += __shfl_xor(sq, 2);
        sq += __shfl_xor(sq, 4);
        sq += __shfl_xor(sq, 8);
        const float sc = (sq/(1.f + sq)) * rsqrtf(sq + EPS);
        out1[(size_t)(pos0 + q*4 + r)*512 + f*DO + n] = v * sc;
    }
}

// ---- kern2: R15-proven body; x from Ph (block-uniform scalar loads). ----------
// writes part2[ch][pos][o][f] fp32
__global__ __launch_bounds__(256) void kern2n(const unsigned short* __restrict__ Ph,
                                              const unsigned short* __restrict__ W2h,
                                              const float* __restrict__ out1,
                                              float* __restrict__ part2)
{
    __shared__ float red[2][4][GP][32];  // 8 KB (dbuf)
    __shared__ float ccs[2][GP][32];     // 2 KB (dbuf)

    const int tid = threadIdx.x;
    const int f  = tid & 31;
    const int og = tid >> 5;            // 0..7
    const int o0 = 2*og, o1 = o0 + 1;
    const int wv = tid >> 6;            // wave 0..3
    const int half = (tid >> 5) & 1;    // og parity within wave
    const int ch = blockIdx.x & (CH-1);
    const int pg = blockIdx.x >> 4;     // 0..71

    int poff[GP];                       // block-uniform -> SGPRs
    #pragma unroll
    for (int p = 0; p < GP; ++p) poff[p] = (pg*GP + p)*KTOT;

    float u0[GP], u1[GP];
    #pragma unroll
    for (int p = 0; p < GP; ++p) {
        const float* up = out1 + (size_t)(pg*GP + p)*512 + f*DO;
        u0[p] = up[o0];
        u1[p] = up[o1];
    }

    const uint4* W2h4 = (const uint4*)W2h;
    const int c0 = ch*CC;

    float acc0[GP], acc1[GP];
    #pragma unroll
    for (int p = 0; p < GP; ++p) { acc0[p] = 0.f; acc1[p] = 0.f; }

    #pragma unroll 1
    for (int cl = 0; cl < CC; ++cl) {
        const int c = c0 + cl;
        const int buf = cl & 1;
        const uint4 w0 = W2h4[(size_t)(c*DO + o0)*F + f];
        const uint4 w1 = W2h4[(size_t)(c*DO + o1)*F + f];

        float pred0[GP], pred1[GP];
        #pragma unroll
        for (int p = 0; p < GP; ++p) {
            const uint4 xv = *(const uint4*)(Ph + poff[p] + c*DI);  // uniform
            pred0[p] = dot8h(w0, xv, 0.f);
            pred1[p] = dot8h(w1, xv, 0.f);
        }

        // agr partial over this thread's two o's; combine og-pairs via xor-32
        #pragma unroll
        for (int p = 0; p < GP; ++p) {
            float ap = pred0[p]*u0[p] + pred1[p]*u1[p];
            ap += __shfl_xor(ap, 32);
            if (half == 0) red[buf][wv][p][f] = ap;
        }
        __syncthreads();

        // remapped role: (p2, f2); finish f-sum, softmax over f, publish cc
        {
            const int p2 = tid >> 5, f2 = tid & 31;
            const float agr = red[buf][0][p2][f2] + red[buf][1][p2][f2]
                            + red[buf][2][p2][f2] + red[buf][3][p2][f2];
            float m = agr;
            m = fmaxf(m, __shfl_xor(m, 1));
            m = fmaxf(m, __shfl_xor(m, 2));
            m = fmaxf(m, __shfl_xor(m, 4));
            m = fmaxf(m, __shfl_xor(m, 8));
            m = fmaxf(m, __shfl_xor(m, 16));
            const float e = __expf(agr - m);
            float s = e;
            s += __shfl_xor(s, 1);
            s += __shfl_xor(s, 2);
            s += __shfl_xor(s, 4);
            s += __shfl_xor(s, 8);
            s += __shfl_xor(s, 16);
            ccs[buf][p2][f2] = e / s;
        }
        __syncthreads();

        // back to (f, og): accumulate cent2
        #pragma unroll
        for (int p = 0; p < GP; ++p) {
            const float cv = ccs[buf][p][f];
            acc0[p] += cv*pred0[p];
            acc1[p] += cv*pred1[p];
        }
    }

    #pragma unroll
    for (int p = 0; p < GP; ++p) {
        const size_t base = ((size_t)(ch*NPOS + pg*GP + p))*DO;
        part2[(base + o0)*F + f] = acc0[p];
        part2[(base + o1)*F + f] = acc1[p];
    }
}

// ---- kern3: reduce cent2 partials ([ch][pos][o][f]), squash, store. -----------
__global__ __launch_bounds__(256) void kern3(const float* __restrict__ part2,
                                             float* __restrict__ out)
{
    const int tid = threadIdx.x;
    const int f = tid & 31, p = tid >> 5;
    const int pos = blockIdx.x*8 + p;

    float cent[DO];
    #pragma unroll
    for (int o = 0; o < DO; ++o) cent[o] = 0.f;
    #pragma unroll 1
    for (int k = 0; k < CH; ++k) {
        const float* s = part2 + (size_t)(k*NPOS + pos)*512 + f;
        #pragma unroll
        for (int o = 0; o < DO; ++o) cent[o] += s[o*F];
    }
    float sn = 0.f;
    #pragma unroll
    for (int o = 0; o < DO; ++o) sn += cent[o]*cent[o];
    const float sc = (sn/(1.f + sn)) * rsqrtf(sn + EPS);
    float* dst = out + ((size_t)pos*F + f)*DO;
    #pragma unroll
    for (int o = 0; o < DO; ++o) dst[o] = cent[o]*sc;
}

// -------- fp32 single-kernel fallback (only if ws too small) -------------------
__device__ __forceinline__ float dot8(const float4* __restrict__ w,
                                      const float4 p0, const float4 p1) {
    float4 a = w[0], b = w[1];
    return a.x*p0.x + a.y*p0.y + a.z*p0.z + a.w*p0.w
         + b.x*p1.x + b.y*p1.y + b.z*p1.z + b.w*p1.w;
}

__global__ __launch_bounds__(256) void capsule_kernel_f32(
    const float* __restrict__ x, const float* __restrict__ Wt,
    float* __restrict__ out)
{
    __shared__ float patch[C*DI];
    __shared__ float cent[F*DO];
    __shared__ float out1[F*DO];
    __shared__ float agr[F*C];
    __shared__ float scale_s[F];

    const int tid = threadIdx.x;
    const int pos = blockIdx.x;
    const int b   = pos / (HO*WO);
    const int rem = pos % (HO*WO);
    const int ho  = rem / WO;
    const int wo  = rem % WO;

    #pragma unroll
    for (int slab = 0; slab < 9; ++slab) {
        const int kh = slab / 3, kw = slab % 3;
        const float* src = x + (((b*H_IN + ho + kh)*W_IN + (wo + kw))*FIN)*DI;
        patch[slab*256 + tid] = src[tid];
    }
    __syncthreads();

    const float4* pv = (const float4*)patch;

    {
        const int fo0 = tid, fo1 = tid + 256;
        const int f0 = fo0 >> 4, o0 = fo0 & 15;
        const int f1 = fo1 >> 4, o1 = fo1 & 15;
        float acc0 = 0.f, acc1 = 0.f;
        for (int c = 0; c < C; ++c) {
            const float4 p0 = pv[c*2], p1 = pv[c*2+1];
            acc0 += dot8((const float4*)(Wt + ((f0*C + c)*DO + o0)*DI), p0, p1);
            acc1 += dot8((const float4*)(Wt + ((f1*C + c)*DO + o1)*DI), p0, p1);
        }
        cent[fo0] = acc0 * (1.f/32.f);
        cent[fo1] = acc1 * (1.f/32.f);
    }
    __syncthreads();

    if (tid < F) {
        float sn = 0.f;
        #pragma unroll
        for (int o = 0; o < DO; ++o) { float v = cent[tid*DO + o]; sn += v*v; }
        const float sc = (sn/(1.f + sn)) * rsqrtf(sn + EPS);
        #pragma unroll
        for (int o = 0; o < DO; ++o) out1[tid*DO + o] = cent[tid*DO + o] * sc;
    }
    __syncthreads();

    #pragma unroll 1
    for (int r = 0; r < (F*C)/256; ++r) {
        const int pp = tid + 256*r;
        const int f = pp / C, c = pp % C;
        const float4* wrow = (const float4*)(Wt + (f*C + c)*DO*DI);
        const float4 p0 = pv[c*2], p1 = pv[c*2+1];
        float a = 0.f;
        #pragma unroll
        for (int o = 0; o < DO; ++o) a += dot8(wrow + o*2, p0, p1) * out1[f*DO + o];
        agr[pp] = a;
    }
    __syncthreads();

    for (int c = tid; c < C; c += 256) {
        float m = -1e30f;
        #pragma unroll
        for (int f = 0; f < F; ++f) m = fmaxf(m, agr[f*C + c]);
        float s = 0.f;
        #pragma unroll
        for (int f = 0; f < F; ++f) {
            const float e = __expf(agr[f*C + c] - m);
            agr[f*C + c] = e; s += e;
        }
        const float inv = 1.f / s;
        #pragma unroll
        for (int f = 0; f < F; ++f) agr[f*C + c] *= inv;
    }
    __syncthreads();

    {
        const int fo0 = tid, fo1 = tid + 256;
        const int f0 = fo0 >> 4, o0 = fo0 & 15;
        const int f1 = fo1 >> 4, o1 = fo1 & 15;
        float acc0 = 0.f, acc1 = 0.f;
        for (int c = 0; c < C; ++c) {
            const float4 p0 = pv[c*2], p1 = pv[c*2+1];
            acc0 += agr[f0*C + c] * dot8((const float4*)(Wt + ((f0*C + c)*DO + o0)*DI), p0, p1);
            acc1 += agr[f1*C + c] * dot8((const float4*)(Wt + ((f1*C + c)*DO + o1)*DI), p0, p1);
        }
        cent[fo0] = acc0;
        cent[fo1] = acc1;
    }
    __syncthreads();

    if (tid < F) {
        float sn = 0.f;
        #pragma unroll
        for (int o = 0; o < DO; ++o) { float v = cent[tid*DO + o]; sn += v*v; }
        scale_s[tid] = (sn/(1.f + sn)) * rsqrtf(sn + EPS);
    }
    __syncthreads();

    out[pos*(F*DO) + tid]       = cent[tid]       * scale_s[tid >> 4];
    out[pos*(F*DO) + tid + 256] = cent[tid + 256] * scale_s[(tid >> 4) + 16];
}

extern "C" void kernel_launch(void* const* d_in, const int* in_sizes, int n_in,
                              void* d_out, int out_size, void* d_ws, size_t ws_size,
                              hipStream_t stream) {
    const float* x  = (const float*)d_in[0];
    const float* Wt = (const float*)d_in[1];
    float* out = (float*)d_out;

    if (ws_size >= W2H_BYTES + WH_BYTES + PH_BYTES + PART_BYTES + OUT1_BYTES) {
        char* p = (char*)d_ws;
        unsigned short* W2h = (unsigned short*)p;            p += W2H_BYTES;
        unsigned short* Wh  = (unsigned short*)p;            p += WH_BYTES;
        unsigned short* Ph  = (unsigned short*)p;            p += PH_BYTES;
        float* part = (float*)p;                             p += PART_BYTES;
        float* out1 = (float*)p;

        kernConv<<<CVT_GRID, 256, 0, stream>>>(Wt, x, W2h, Wh, Ph);  // 1800 blocks
        kernM1<<<36*8, 256, 0, stream>>>(Ph, Wh, out1);              // 288 blocks
        kern2n<<<GRID, 256, 0, stream>>>(Ph, W2h, out1, part);       // 1152 blocks
        kern3<<<NPOS/8, 256, 0, stream>>>(part, out);                // 72 blocks
    } else {
        capsule_kernel_f32<<<NPOS, 256, 0, stream>>>(x, Wt, out);
    }
}